// Round 36
// baseline (128.139 us; speedup 1.0000x reference)
//
#include <hip/hip_runtime.h>
#include <hip/hip_bf16.h>

// MultiHeadAttention fused pipeline, MI355X gfx950.
// B=8, S=1024 (N=1023 + 1 global), HID=512, H=8, D=64.
// Stages: qkv_proj 64x128 tiles (1536 blocks ~5/CU) -> qh/kh/vht2;
//         ab_u8 (streaming narrow) -> ab8 u8 [B][1024q][1024t];
//         attn_fused (LDS-staged, dbuf, b-keyed XCD, [q][t'] ab tile) -> partials;
//         out_proj 64x128 tiles (512 blocks = 2/CU) -> f32 out.
// Ladder: 194 -> 148 -> 128.2 -> 124.6 -> 121.3 -> 121.1 -> 115.5 (R35 out_proj
//         grid fix: 256->512 blocks, -5.6us -> grid-starvation mechanism VALIDATED).
// R36: same mechanism on qkv. 768 blocks = 3/CU, 27% occ, 20% HBM = latency-
//   bound, too few in-flight loads. M-tile 128->64 (dbuf 1-barrier loop shape
//   UNchanged): grid 1536, LDS 30720 (5/CU cap), A-staging halves per thread,
//   wave-tile 32x64 (acc 32 VGPR). Weight re-reads double but L2-resident.
//   Gate: qkv >= 52us or VGPR < 56 (de-pipeline) => revert to R35.

typedef __attribute__((ext_vector_type(8)))  __bf16 bf16x8;
typedef __attribute__((ext_vector_type(16))) float  f32x16;

__device__ inline f32x16 zero16(){
  f32x16 z;
  #pragma unroll
  for (int i=0;i<16;i++) z[i] = 0.0f;
  return z;
}

__device__ inline unsigned short f2bf(float x){           // RNE f32->bf16
  unsigned u = __float_as_uint(x);
  u += 0x7fffu + ((u>>16)&1u);
  return (unsigned short)(u>>16);
}
__device__ inline unsigned f2bf_pair(float a, float b){   // pack 2 bf16 into dword (RNE)
  unsigned ua = __float_as_uint(a); ua += 0x7fffu + ((ua>>16)&1u);
  unsigned ub = __float_as_uint(b); ub += 0x7fffu + ((ub>>16)&1u);
  return (ua>>16) | (ub & 0xffff0000u);
}
// combine two packed-bf16 dwords: (a+b)*rn per element, repacked bf16
__device__ inline unsigned comb2(unsigned a, unsigned b, float rn){
  const float a0 = __uint_as_float(a<<16), a1 = __uint_as_float(a & 0xffff0000u);
  const float b0 = __uint_as_float(b<<16), b1 = __uint_as_float(b & 0xffff0000u);
  return f2bf_pair((a0+b0)*rn, (a1+b1)*rn);
}

__device__ inline void bar_lgkm(){   // LDS-visibility barrier WITHOUT vmcnt drain
  asm volatile("s_waitcnt lgkmcnt(0)" ::: "memory");
  __builtin_amdgcn_s_barrier();
}

// ---------------------------------------------------------------------------
// ab_u8: ab8[b][q][t] = (q<1023 && t<1023) ? (u8)ab[b][q][t] : 255.
// NO transpose, NO LDS: pure streaming narrow. 2048 blocks x 256 thr.
// ---------------------------------------------------------------------------
__global__ __launch_bounds__(256)
void ab_u8(const int* ab, unsigned char* ab8)
{
  const int k   = blockIdx.x;          // 2048 = 8 b x 256 row-groups
  const int b   = k >> 8;
  const int q   = ((k & 255) << 2) + (threadIdx.x >> 6);
  const int j   = threadIdx.x & 63;
  const bool qok = (q < 1023);
  const int* rowp = ab + ((size_t)b*1023 + q)*1023;
  unsigned char* outp = ab8 + ((size_t)b << 20) + (size_t)q*1024;
  #pragma unroll
  for (int i = 0; i < 4; ++i){
    const int t0 = (j + 64*i)*4;       // out byte base 0..1020
    unsigned o = 0;
    #pragma unroll
    for (int c = 0; c < 4; ++c){
      const int t = t0 + c;
      int v = 255;
      if (qok && t < 1023) v = rowp[t];
      o |= ((unsigned)v & 255u) << (8*c);
    }
    *(unsigned*)(outp + t0) = o;
  }
}

// ---------------------------------------------------------------------------
// Merged Q/K/V projection, 64x128 tiles (R36): 1536 blocks, 256 threads,
// DOUBLE-BUFFERED LDS, ONE barrier per K-step (R26-proven loop shape).
// sel = bid>>9: 0: qh = (q Wq^T + bq)*scaleq; 1: kh; 2 (swapped): vht2.
// sel0/1: r0 = (t&127)*64, c0 = (t>>7)*128.  sel2: r0 = (t&7)*64, c0 = (t>>3)*128.
// A-staging: 4 thr/row (8 floats = 2 float4 -> 4 cvt -> 1 uint4 LDS write).
// B-staging: 2 thr/row, 16 floats (unchanged). Wave-tile 32x64, 4 MFMA/step.
// ---------------------------------------------------------------------------
__global__ __launch_bounds__(256)
void qkv_proj(const float* xq, const float* xk, const float* xv,
              const float* Wq, const float* Wk, const float* Wv,
              const float* bq, const float* bk, const float* bv,
              unsigned short* qh, unsigned short* kh, unsigned short* vht2,
              float scaleq)
{
  __shared__ unsigned short lda[2][64*40];    // 40-pad rows (5120 B each)
  __shared__ unsigned short ldb[2][128*40];   // (10240 B each)
  const int bid = blockIdx.x;
  const int sel = bid >> 9;                // uniform per block
  const int t   = bid & 511;
  const float *RA, *RB, *bias;
  int r0, c0;
  if (sel == 0){ RA = xq; RB = Wq; bias = bq; r0 = (t&127)*64; c0 = (t>>7)*128; }
  else if (sel == 1){ RA = xk; RB = Wk; bias = bk; r0 = (t&127)*64; c0 = (t>>7)*128; }
  else { RA = Wv; RB = xv; bias = bv; r0 = (t&7)*64; c0 = (t>>3)*128; }

  const int tid  = threadIdx.x;
  const int w    = tid>>6, lane = tid&63, lo = lane&31, hi = lane>>5;
  const int wr   = (w>>1)*32, wc = (w&1)*64;
  const int arow = tid>>2, kba = (tid&3)*8;   // A: 4 thr/row, 8 floats each
  const int brow = tid>>1, kbb = (tid&1)*16;  // B: 2 thr/row, 16 floats each

  f32x16 acc2[2];
  acc2[0] = zero16(); acc2[1] = zero16();

  float4 ra[2], rb4[4];

  // ---- prologue: load tile0; stage into buf0; load tile1; barrier ----
  {
    const float4* p = (const float4*)(RA + (size_t)(r0+arow)*512 + kba);
    ra[0]=p[0]; ra[1]=p[1];
    const float4* pq = (const float4*)(RB + (size_t)(c0+brow)*512 + kbb);
    rb4[0]=pq[0]; rb4[1]=pq[1]; rb4[2]=pq[2]; rb4[3]=pq[3];
  }
  {
    uint4 w0;
    w0.x = f2bf_pair(ra[0].x, ra[0].y); w0.y = f2bf_pair(ra[0].z, ra[0].w);
    w0.z = f2bf_pair(ra[1].x, ra[1].y); w0.w = f2bf_pair(ra[1].z, ra[1].w);
    *(uint4*)&lda[0][arow*40 + kba] = w0;
    uint4 v0, v1;
    v0.x = f2bf_pair(rb4[0].x, rb4[0].y); v0.y = f2bf_pair(rb4[0].z, rb4[0].w);
    v0.z = f2bf_pair(rb4[1].x, rb4[1].y); v0.w = f2bf_pair(rb4[1].z, rb4[1].w);
    v1.x = f2bf_pair(rb4[2].x, rb4[2].y); v1.y = f2bf_pair(rb4[2].z, rb4[2].w);
    v1.z = f2bf_pair(rb4[3].x, rb4[3].y); v1.w = f2bf_pair(rb4[3].z, rb4[3].w);
    uint4* pb = (uint4*)&ldb[0][brow*40 + kbb];
    pb[0] = v0; pb[1] = v1;
  }
  {
    const float4* p = (const float4*)(RA + (size_t)(r0+arow)*512 + 32 + kba);
    ra[0]=p[0]; ra[1]=p[1];
    const float4* pq = (const float4*)(RB + (size_t)(c0+brow)*512 + 32 + kbb);
    rb4[0]=pq[0]; rb4[1]=pq[1]; rb4[2]=pq[2]; rb4[3]=pq[3];
  }
  bar_lgkm();   // buf0 visible

  for (int ks=0; ks<16; ++ks){
    const int cur = ks & 1;
    // stage tile ks+1 into the OTHER buffer (regs loaded last iter)
    if (ks < 15){
      uint4 w0;
      w0.x = f2bf_pair(ra[0].x, ra[0].y); w0.y = f2bf_pair(ra[0].z, ra[0].w);
      w0.z = f2bf_pair(ra[1].x, ra[1].y); w0.w = f2bf_pair(ra[1].z, ra[1].w);
      *(uint4*)&lda[cur^1][arow*40 + kba] = w0;
      uint4 v0, v1;
      v0.x = f2bf_pair(rb4[0].x, rb4[0].y); v0.y = f2bf_pair(rb4[0].z, rb4[0].w);
      v0.z = f2bf_pair(rb4[1].x, rb4[1].y); v0.w = f2bf_pair(rb4[1].z, rb4[1].w);
      v1.x = f2bf_pair(rb4[2].x, rb4[2].y); v1.y = f2bf_pair(rb4[2].z, rb4[2].w);
      v1.z = f2bf_pair(rb4[3].x, rb4[3].y); v1.w = f2bf_pair(rb4[3].z, rb4[3].w);
      uint4* pb = (uint4*)&ldb[cur^1][brow*40 + kbb];
      pb[0] = v0; pb[1] = v1;
    }
    // issue loads for tile ks+2 (in flight across the barrier)
    if (ks < 14){
      const int k0 = (ks+2)*32;
      const float4* p = (const float4*)(RA + (size_t)(r0+arow)*512 + k0 + kba);
      ra[0]=p[0]; ra[1]=p[1];
      const float4* pq = (const float4*)(RB + (size_t)(c0+brow)*512 + k0 + kbb);
      rb4[0]=pq[0]; rb4[1]=pq[1]; rb4[2]=pq[2]; rb4[3]=pq[3];
    }
    // MFMA from current buffer (visible via previous barrier)
    #pragma unroll
    for (int kf=0; kf<2; ++kf){
      bf16x8 af  = *(const bf16x8*)&lda[cur][(wr+lo)*40    + kf*16 + hi*8];
      bf16x8 bg0 = *(const bf16x8*)&ldb[cur][(wc+lo)*40    + kf*16 + hi*8];
      bf16x8 bg1 = *(const bf16x8*)&ldb[cur][(wc+32+lo)*40 + kf*16 + hi*8];
      acc2[0] = __builtin_amdgcn_mfma_f32_32x32x16_bf16(af, bg0, acc2[0], 0,0,0);
      acc2[1] = __builtin_amdgcn_mfma_f32_32x32x16_bf16(af, bg1, acc2[1], 0,0,0);
    }
    // ONE barrier: my reads of buf[cur] + writes of buf[cur^1] all drained
    bar_lgkm();
  }

  // epilogue; C/D layout: col = lane&31, row = (r&3)+8*(r>>2)+4*(lane>>5)
  #pragma unroll
  for (int ni=0;ni<2;ni++){
    #pragma unroll
    for (int r=0;r<16;r++){
      const int rl = wr + (r&3) + 8*(r>>2) + 4*hi;
      const int cl = wc + ni*32 + lo;
      const int rg = r0 + rl, cg = c0 + cl;
      float v = acc2[ni][r];
      if (sel == 0){
        v = (v + bias[cg]) * scaleq;
        const int bb = rg>>10, s = rg&1023, h = cg>>6, d = cg&63;
        qh[(((bb*8+h)*1024)+s)*64 + d] = f2bf(v);
      } else if (sel == 1){
        v = v + bias[cg];
        const int bb = rg>>10, s = rg&1023, h = cg>>6, d = cg&63;
        kh[(((bb*8+h)*1024)+s)*64 + d] = f2bf(v);
      } else {
        v = v + bias[rg];
        const int h = rg>>6, d = rg&63, bb = cg>>10, s = cg&1023;
        vht2[(((size_t)(bb*8+h)*32 + (s>>5))*64 + d)*32 + (s&31)] = f2bf(v);
      }
    }
  }
}

// ---------------------------------------------------------------------------
// Out projection, 64x128 tiles (R35): 512 blocks (dim3(128,4)) = 2 blocks/CU.
//   A[row][k] = (ctx0[row][k] + ctx1[row][k]) / (l0[b,h,s] + l1[b,h,s])
//   out[8192][512] = A Wo^T + bo (f32).
// ---------------------------------------------------------------------------
__global__ __launch_bounds__(256)
void out_proj(const unsigned short* ctx0, const unsigned short* ctx1,
              const float* lsump, const float* Wo, const float* bo, float* OUT)
{
  __shared__ unsigned short lda[64*40];
  __shared__ unsigned short ldb[128*40];
  const int tid  = threadIdx.x;
  const int r0   = blockIdx.x*64, c0 = blockIdx.y*128;
  const int w    = tid>>6, lane = tid&63, lo = lane&31, hi = lane>>5;
  const int wr   = (w>>1)*32, wc = (w&1)*64;
  const int arow2 = tid>>2, kb2 = (tid&3)*8;    // A: 4 thr/row, 8 bf16 each
  const int brow  = tid>>1, kbb = (tid&1)*16;   // B: 2 thr/row, 16 f32 each
  const int rgs  = r0 + arow2, bb = rgs>>10, ss = rgs&1023;
  const float* lb0 = lsump + (size_t)(bb*8)*1024 + ss;        // ts=0, + h*1024
  const float* lb1 = lsump + (size_t)((8+bb)*8)*1024 + ss;    // ts=1

  f32x16 acc2[2];
  acc2[0] = zero16(); acc2[1] = zero16();

  uint4 ca0, ca1;
  float4 rb4[4];
  float l0, l1;

  {
    ca0 = *(const uint4*)(ctx0 + rgs*512 + kb2);
    ca1 = *(const uint4*)(ctx1 + rgs*512 + kb2);
    const int h = kb2>>6;                        // = 0
    l0 = lb0[h*1024]; l1 = lb1[h*1024];
    const float4* pq = (const float4*)(Wo + (c0+brow)*512 + kbb);
    rb4[0]=pq[0]; rb4[1]=pq[1]; rb4[2]=pq[2]; rb4[3]=pq[3];
  }

  for (int ks=0; ks<16; ++ks){
    bar_lgkm();
    {
      const float rn = __builtin_amdgcn_rcpf(l0 + l1);
      uint4 w0;
      w0.x = comb2(ca0.x, ca1.x, rn); w0.y = comb2(ca0.y, ca1.y, rn);
      w0.z = comb2(ca0.z, ca1.z, rn); w0.w = comb2(ca0.w, ca1.w, rn);
      *(uint4*)&lda[arow2*40 + kb2] = w0;
      uint4 v0, v1;
      v0.x = f2bf_pair(rb4[0].x, rb4[0].y); v0.y = f2bf_pair(rb4[0].z, rb4[0].w);
      v0.z = f2bf_pair(rb4[1].x, rb4[1].y); v0.w = f2bf_pair(rb4[1].z, rb4[1].w);
      v1.x = f2bf_pair(rb4[2].x, rb4[2].y); v1.y = f2bf_pair(rb4[2].z, rb4[2].w);
      v1.z = f2bf_pair(rb4[3].x, rb4[3].y); v1.w = f2bf_pair(rb4[3].z, rb4[3].w);
      uint4* pb = (uint4*)&ldb[brow*40 + kbb];
      pb[0] = v0; pb[1] = v1;
    }
    if (ks < 15){
      const int k0 = (ks+1)*32;
      ca0 = *(const uint4*)(ctx0 + rgs*512 + k0 + kb2);
      ca1 = *(const uint4*)(ctx1 + rgs*512 + k0 + kb2);
      const int h = (k0+kb2)>>6;
      l0 = lb0[h*1024]; l1 = lb1[h*1024];
      const float4* pq = (const float4*)(Wo + (c0+brow)*512 + k0 + kbb);
      rb4[0]=pq[0]; rb4[1]=pq[1]; rb4[2]=pq[2]; rb4[3]=pq[3];
    }
    bar_lgkm();
    #pragma unroll
    for (int kf=0; kf<2; ++kf){
      bf16x8 af  = *(const bf16x8*)&lda[(wr+lo)*40    + kf*16 + hi*8];
      bf16x8 bg0 = *(const bf16x8*)&ldb[(wc+lo)*40    + kf*16 + hi*8];
      bf16x8 bg1 = *(const bf16x8*)&ldb[(wc+32+lo)*40 + kf*16 + hi*8];
      acc2[0] = __builtin_amdgcn_mfma_f32_32x32x16_bf16(af, bg0, acc2[0], 0,0,0);
      acc2[1] = __builtin_amdgcn_mfma_f32_32x32x16_bf16(af, bg1, acc2[1], 0,0,0);
    }
  }

  #pragma unroll
  for (int ni=0;ni<2;ni++){
    #pragma unroll
    for (int r=0;r<16;r++){
      const int rl = wr + (r&3) + 8*(r>>2) + 4*hi;
      const int cl = wc + ni*32 + lo;
      const int rg = r0 + rl, cg = c0 + cl;
      OUT[rg*512 + cg] = acc2[ni][r] + bo[cg];
    }
  }
}

// ---------------------------------------------------------------------------
// Fused attention, LDS-STAGED + DOUBLE-BUFFERED (1 barrier/iter), u8 ab8.
// 1024 blocks x 256 thr = 4 waves; block = ONE head x FOUR q-tiles.
// XCD decode keyed on b: b = m&7. r = m>>3: h = r&7, ts = (r>>3)&1, sg = r>>4.
// kls stride 72 (ushort); vls stride 40 (ushort); abls [q 0..127][t' 0..31]
// u8 stride 36 (q-major so the gather is 4 x ds_read_b32, not 16 x u8).
// tbl[0..254] = table*log2e, tbl[255] = vbias*log2e (boundary sentinel).
// ---------------------------------------------------------------------------
__global__ __launch_bounds__(256)
void attn_fused(const unsigned short* qh, const unsigned short* kh,
                const unsigned short* vht2, const unsigned char* ab8,
                const float* bias_table, const float* vbias,
                unsigned short* ctxp, float* lsump)
{
  __shared__ float tbl[256];                // [0..254]=table*log2e, 255=vbias
  __shared__ unsigned short kls[2][32*72];  // K tile [t'][d]
  __shared__ unsigned short vls[2][64*40];  // V tile [d][t']
  __shared__ unsigned char  abls[2][128*36];// ab tile [q 0..127][t' 0..31], u8

  const int tid = threadIdx.x;
  const int m   = blockIdx.x;
  const int b   = m & 7;                 // XCD key: all 128 blocks of b co-XCD
  const int r   = m >> 3;
  const int h   = r & 7;
  const int ts  = (r >> 3) & 1;
  const int sg  = r >> 4;                // q-group 0..7
  const int tb  = ts*512;
  const int q0  = sg*128;

  {
    const int i = tid;                   // 256 threads cover 256 entries
    float v = (i < 255) ? bias_table[i*8 + h] : vbias[h];
    tbl[i] = v * 1.4426950408889634f;
  }

  const int w = tid>>6, lane = tid&63, lo = lane&31, hi = lane>>5;
  const bool hib = (hi != 0);
  const int s0 = q0 + w*32;              // this wave's q-tile base

  const unsigned short* qbase  = qh   + (size_t)(b*8+h)*65536;
  const unsigned short* kbase  = kh   + (size_t)(b*8+h)*65536 + (size_t)tb*64;
  const unsigned short* vbase  = vht2 + ((size_t)(b*8+h)*32 + (tb>>5))*2048;
  const unsigned char*  abbase = ab8  + ((size_t)b<<20);   // [q][t]

  // Q fragments (B operand; Q[q = s0+lo][d-chunk]) — loaded once
  bf16x8 qf[4];
  #pragma unroll
  for (int kf=0; kf<4; ++kf)
    qf[kf] = *(const bf16x8*)&qbase[(s0+lo)*64 + kf*16 + hi*8];

  f32x16 accv[2]; accv[0] = zero16(); accv[1] = zero16();
  float lsum = 0.0f;

  // staging addresses (coalesced; 16B per thread per structure)
  const int kdst = (tid>>3)*72  + (tid&7)*8;    // K: row t'=tid/8, col d=(tid%8)*8
  const int vdst = (tid>>2)*40  + (tid&3)*8;    // V: row d=tid/4, col t'=(tid%4)*8
  const int adst = (tid>>1)*36  + (tid&1)*16;   // ab u8: row q'=tid/2, 16 t' each
  const size_t asrc = (size_t)(q0 + (tid>>1))*1024 + (tid&1)*16;  // + tb + tt

  // ---- prologue: load tile 0, stage into buf0, issue tile-1 loads, barrier ----
  uint4 krg, vrg, ar0;
  krg = *(const uint4*)&kbase[tid*8];
  vrg = *(const uint4*)&vbase[tid*8];
  ar0 = *(const uint4*)&abbase[asrc + tb];
  *(uint4*)&kls[0][kdst]  = krg;
  *(uint4*)&vls[0][vdst]  = vrg;
  *(uint4*)&abls[0][adst] = ar0;
  krg = *(const uint4*)&kbase[32*64 + tid*8];
  vrg = *(const uint4*)&vbase[2048 + tid*8];
  ar0 = *(const uint4*)&abbase[asrc + tb + 32];
  bar_lgkm();   // buf0 visible (also covers tbl)

  for (int tt=0; tt<512; tt+=32){
    const int cur = (tt>>5) & 1;
    // stage tile tt+32 into the OTHER buffer (vmcnt wait here, ~1 iter slack);
    // that buffer's iter-(tt-32) readers finished before the last barrier.
    *(uint4*)&kls[cur^1][kdst]  = krg;
    *(uint4*)&vls[cur^1][vdst]  = vrg;
    *(uint4*)&abls[cur^1][adst] = ar0;
    // issue loads for tile tt+64 (wrapped; extras on last iters harmless)
    {
      const int tn = (tt+64)&511;
      krg = *(const uint4*)&kbase[tn*64 + tid*8];
      vrg = *(const uint4*)&vbase[(tn>>5)*2048 + tid*8];
      ar0 = *(const uint4*)&abbase[asrc + tb + tn];
    }

    // QK^T swapped: sc[r] = S[t = tt + crow(r,hi)][q = s0+lo] (from buf[cur])
    f32x16 sc = zero16();
    #pragma unroll
    for (int kf=0; kf<4; ++kf){
      bf16x8 kfr = *(const bf16x8*)&kls[cur][lo*72 + kf*16 + hi*8];
      sc = __builtin_amdgcn_mfma_f32_32x32x16_bf16(kfr, qf[kf], sc, 0,0,0);
    }

    // bias gather: one u32 per g covers t' = 8g+4hi .. +3 (q-major tile)
    const unsigned char* abrow = &abls[cur][(w*32 + lo)*36];
    unsigned d[4][2];
    float ls = 0.0f;
    #pragma unroll
    for (int g=0; g<4; ++g){
      const unsigned v4 = *(const unsigned*)(abrow + 8*g + 4*hi);
      float p[4];
      #pragma unroll
      for (int u=0; u<4; ++u){
        const int idx = (v4 >> (8*u)) & 255;
        p[u] = __builtin_amdgcn_exp2f(sc[4*g+u] + tbl[idx]);
        ls  += p[u];
      }
      d[g][0] = f2bf_pair(p[0], p[1]);
      d[g][1] = f2bf_pair(p[2], p[3]);
    }
    lsum += ls;

    // exchange with partner lane (lo, 1-hi)
    unsigned x[4][2];
    #pragma unroll
    for (int g=0; g<4; ++g){
      x[g][0] = __shfl_xor(d[g][0], 32, 64);
      x[g][1] = __shfl_xor(d[g][1], 32, 64);
    }

    // PV: A-frag(c2) = hi ? {x[2c2+1], d[2c2+1]} : {d[2c2], x[2c2]}
    #pragma unroll
    for (int c2=0; c2<2; ++c2){
      union { unsigned u[4]; bf16x8 v; } pc;
      pc.u[0] = hib ? x[2*c2+1][0] : d[2*c2][0];
      pc.u[1] = hib ? x[2*c2+1][1] : d[2*c2][1];
      pc.u[2] = hib ? d[2*c2+1][0] : x[2*c2][0];
      pc.u[3] = hib ? d[2*c2+1][1] : x[2*c2][1];
      bf16x8 vf0 = *(const bf16x8*)&vls[cur][(     lo)*40 + c2*16 + hi*8];
      bf16x8 vf1 = *(const bf16x8*)&vls[cur][(32 + lo)*40 + c2*16 + hi*8];
      accv[0] = __builtin_amdgcn_mfma_f32_32x32x16_bf16(pc.v, vf0, accv[0], 0,0,0);
      accv[1] = __builtin_amdgcn_mfma_f32_32x32x16_bf16(pc.v, vf1, accv[1], 0,0,0);
    }
    // ONE barrier: my reads of buf[cur] + writes of buf[cur^1] all drained
    bar_lgkm();
  }

  // full partial row sum for q = s0+lo (combine the two hi-halves)
  lsum += __shfl_xor(lsum, 32, 64);

  // store UNNORMALIZED partial ctx bf16 (rows q = crow(r,hi), col d = lo)
  unsigned short* cbase = ctxp + (size_t)ts*4194304;   // 8*1024*512 per half
  #pragma unroll
  for (int dc=0; dc<2; ++dc){
    #pragma unroll
    for (int r2=0;r2<16;r2++){
      const int rq = (r2&3) + 8*(r2>>2) + 4*hi;
      cbase[((size_t)b*1024 + s0 + rq)*512 + h*64 + dc*32 + lo] = f2bf(accv[dc][r2]);
    }
  }
  if (hi == 0){
    lsump[((size_t)(ts*8 + b)*8 + h)*1024 + s0 + lo] = lsum;
  }
}

extern "C" void kernel_launch(void* const* d_in, const int* in_sizes, int n_in,
                              void* d_out, int out_size, void* d_ws, size_t ws_size,
                              hipStream_t stream)
{
  const float* q    = (const float*)d_in[0];
  const float* k    = (const float*)d_in[1];
  const float* v    = (const float*)d_in[2];
  const int*   ab   = (const int*)  d_in[3];
  const float* Wq   = (const float*)d_in[4];
  const float* bq   = (const float*)d_in[5];
  const float* Wk   = (const float*)d_in[6];
  const float* bk   = (const float*)d_in[7];
  const float* Wv   = (const float*)d_in[8];
  const float* bv   = (const float*)d_in[9];
  const float* Wo   = (const float*)d_in[10];
  const float* bo   = (const float*)d_in[11];
  const float* btab = (const float*)d_in[12];
  const float* vbia = (const float*)d_in[13];

  char* ws = (char*)d_ws;
  unsigned short* qh   = (unsigned short*)(ws);                    //  8 MB
  unsigned short* kh   = (unsigned short*)(ws + ((size_t) 8<<20)); //  8 MB
  unsigned short* vht2 = (unsigned short*)(ws + ((size_t)16<<20)); //  8 MB
  unsigned short* ctxp = (unsigned short*)(ws + ((size_t)24<<20)); // 16 MB (2 halves)
  float*          lsmp = (float*)         (ws + ((size_t)40<<20)); // 512 KB
  unsigned char*  ab8  = (unsigned char*) (ws + ((size_t)41<<20)); //  8 MB (u8)

  const float SCALE_Q = 0.125f * 1.4426950408889634f;  // D^-0.5 * log2(e)

  qkv_proj<<<1536, 256, 0, stream>>>(q, k, v, Wq, Wk, Wv, bq, bk, bv,
                                     qh, kh, vht2, SCALE_Q);
  ab_u8<<<2048, 256, 0, stream>>>(ab, ab8);
  attn_fused<<<1024, 256, 0, stream>>>(qh, kh, vht2, ab8, btab, vbia,
                                       ctxp, lsmp);
  out_proj<<<dim3(128,4), 256, 0, stream>>>(ctxp, ctxp + (size_t)4194304,
                                            lsmp, Wo, bo, (float*)d_out);
}